// Round 12
// baseline (124.817 us; speedup 1.0000x reference)
//
#include <hip/hip_runtime.h>

// KMeans soft-assignment via bf16 hi/lo split MFMA (3 passes), fused softmax.
// logits = (2*x.c - ||c||^2)/T, T=0.1; ||x||^2 cancels in softmax.
// R12: NO K-loop LDS. B fragments loaded straight to registers from a
// chunk-major table (contiguous 1 KB per wave-tile read, L1-shared across
// waves/blocks); __syncthreads as the batch fence so the compiler can't sink
// the loads (R5/R6 failure). acc=128 AGPR + ~110 arch -> 2 waves/SIMD clean.
// x: [32768,256] f32, c: [512,256] f32, out: [32768,512] f32
#define NROWS 32768
#define KC 512
#define DDIM 256
#define BM 64
#define BK 16
#define KCH (DDIM / BK)        // 16 k-chunks
#define CHUNK_USH (KC * BK)    // 8192 ushorts = 16 KB per chunk table

typedef __attribute__((ext_vector_type(8)))  short bf16x8;
typedef __attribute__((ext_vector_type(16))) float f32x16;

union U8 { unsigned short u[8]; bf16x8 v; };

__device__ __forceinline__ unsigned short f2bf(float f) {   // RNE f32->bf16
    union { float f; unsigned int u; } a; a.f = f;
    unsigned int r = a.u + 0x7fffu + ((a.u >> 16) & 1u);
    return (unsigned short)(r >> 16);
}
__device__ __forceinline__ float bf2f(unsigned short h) {
    union { unsigned int u; float f; } a; a.u = ((unsigned int)h) << 16;
    return a.f;
}

// ---- prep: c -> chunk-major bf16 hi/lo tables + csq10 ----
// octet (col n, half h) of chunk ks at ushort offset:
//   ks*CHUNK_USH + (n>>5)*512 + (h*32 + (n&31))*8     (lane-identity layout)
__global__ __launch_bounds__(64) void prep_c(const float* __restrict__ c,
                                             unsigned short* __restrict__ bhi,
                                             unsigned short* __restrict__ blo,
                                             float* __restrict__ csq10) {
    const int n = blockIdx.x, lane = threadIdx.x;
    const int d0 = lane * 4;
    float4 v = ((const float4*)(c + (size_t)n * DDIM))[lane];
    float vv[4] = {v.x, v.y, v.z, v.w};
    unsigned short hh[4], ll[4];
    float ssq = 0.f;
    #pragma unroll
    for (int i = 0; i < 4; ++i) {
        ssq += vv[i] * vv[i];
        hh[i] = f2bf(vv[i]);
        ll[i] = f2bf(vv[i] - bf2f(hh[i]));
    }
    #pragma unroll
    for (int off = 32; off; off >>= 1) ssq += __shfl_xor(ssq, off);
    if (lane == 0) csq10[n] = 10.f * ssq;
    const int ks = d0 >> 4;                 // 0..15
    const int h  = (d0 >> 3) & 1;           // k-octet half
    const int j0 = d0 & 7;                  // 0 or 4
    const size_t dst = (size_t)ks * CHUNK_USH + (n >> 5) * 512 +
                       (h * 32 + (n & 31)) * 8 + j0;
    *(ushort4*)(bhi + dst) = make_ushort4(hh[0], hh[1], hh[2], hh[3]);
    *(ushort4*)(blo + dst) = make_ushort4(ll[0], ll[1], ll[2], ll[3]);
}

// ---- main: 512 blocks x 256 threads (4 waves = 2 M-groups x 2 N-halves) ----
// wave (wm,wn): rows wm*32..+31, cols wn*256..+255 (8 tiles of 32), 32x32x16
__global__ __launch_bounds__(256, 2) void kmeans_mfma(
    const float* __restrict__ x, const unsigned short* __restrict__ bhi,
    const unsigned short* __restrict__ blo, const float* __restrict__ csq10,
    float* __restrict__ out) {
    __shared__ float  lbuf[16 * 516];             // 33 KB transpose buffer
    __shared__ float  red0[2][BM], red1[2][BM];   // 1 KB
    __shared__ float2 MI[BM];                     // 0.5 KB

    const int tid  = threadIdx.x;
    const int w    = tid >> 6, lane = tid & 63;
    const int wm   = w >> 1, wn = w & 1;
    const int c5   = lane & 31, h = lane >> 5;
    const int row0 = blockIdx.x * BM;

    f32x16 acc[8];
    #pragma unroll
    for (int t = 0; t < 8; ++t)
        #pragma unroll
        for (int r = 0; r < 16; ++r) acc[t][r] = 0.f;

    // A: lane owns row (row0 + wm*32 + c5), k-octet h*8 of each 16-k chunk
    const float* xrow = x + (size_t)(row0 + wm * 32 + c5) * DDIM + h * 8;
    // B: wave's tile t read = contiguous 1 KB; lane offset = lane*8 ushorts
    const unsigned short* bhB = bhi + (wn * 8) * 512 + lane * 8;
    const unsigned short* blB = blo + (wn * 8) * 512 + lane * 8;

    for (int ks = 0; ks < KCH; ++ks) {
        const size_t cb = (size_t)ks * CHUNK_USH;
        // batch-issue all loads for this chunk (fence below forces issue+drain)
        bf16x8 bh[8], bl[8];
        #pragma unroll
        for (int t = 0; t < 8; ++t) bh[t] = *(const bf16x8*)(bhB + cb + t * 512);
        #pragma unroll
        for (int t = 0; t < 8; ++t) bl[t] = *(const bf16x8*)(blB + cb + t * 512);
        float4 a0 = *(const float4*)(xrow + ks * BK);
        float4 a1 = *(const float4*)(xrow + ks * BK + 4);
        __syncthreads();   // scheduling fence: single vmcnt drain for the batch

        // convert A to hi/lo fragments
        bf16x8 ah, al;
        {
            float v8[8] = {a0.x, a0.y, a0.z, a0.w, a1.x, a1.y, a1.z, a1.w};
            U8 H, L;
            #pragma unroll
            for (int i = 0; i < 8; ++i) {
                H.u[i] = f2bf(v8[i]);
                L.u[i] = f2bf(v8[i] - bf2f(H.u[i]));
            }
            ah = H.v; al = L.v;
        }
        // 3-pass MFMA over 8 col-tiles
        #pragma unroll
        for (int t = 0; t < 8; ++t) {
            acc[t] = __builtin_amdgcn_mfma_f32_32x32x16_bf16(ah, bh[t], acc[t], 0, 0, 0);
            acc[t] = __builtin_amdgcn_mfma_f32_32x32x16_bf16(ah, bl[t], acc[t], 0, 0, 0);
            acc[t] = __builtin_amdgcn_mfma_f32_32x32x16_bf16(al, bh[t], acc[t], 0, 0, 0);
        }
    }

    // ---- softmax stats; C/D: col = wn*256+t*32+c5, row = (r&3)+8*(r>>2)+4h
    float csqv[8];
    #pragma unroll
    for (int t = 0; t < 8; ++t) csqv[t] = csq10[wn * 256 + t * 32 + c5];

    #pragma unroll
    for (int r = 0; r < 16; ++r) {
        float pm = -1e30f;
        #pragma unroll
        for (int t = 0; t < 8; ++t) pm = fmaxf(pm, 20.f * acc[t][r] - csqv[t]);
        #pragma unroll
        for (int off = 1; off < 32; off <<= 1) pm = fmaxf(pm, __shfl_xor(pm, off));
        if (c5 == 0) red0[wn][wm * 32 + (r & 3) + 8 * (r >> 2) + 4 * h] = pm;
    }
    __syncthreads();
    #pragma unroll
    for (int r = 0; r < 16; ++r) {
        const int   row = wm * 32 + (r & 3) + 8 * (r >> 2) + 4 * h;
        const float Mf  = fmaxf(red0[0][row], red0[1][row]);
        float ps = 0.f;
        #pragma unroll
        for (int t = 0; t < 8; ++t) ps += __expf(20.f * acc[t][r] - csqv[t] - Mf);
        #pragma unroll
        for (int off = 1; off < 32; off <<= 1) ps += __shfl_xor(ps, off);
        if (c5 == 0) red1[wn][row] = ps;
    }
    __syncthreads();
    if (tid < BM) {
        const float Mf = fmaxf(red0[0][tid], red0[1][tid]);
        const float Sf = red1[0][tid] + red1[1][tid];
        MI[tid] = make_float2(Mf, 1.f / Sf);
    }
    __syncthreads();

    // ---- transpose epilogue: 4 passes of 16 rows through lbuf ----
    #pragma unroll
    for (int p = 0; p < 4; ++p) {
        if (wm == (p >> 1)) {
            #pragma unroll
            for (int i = 0; i < 8; ++i) {
                const int    rr = (p & 1) * 8 + i;                 // acc reg
                const int    lr = (i & 3) + 8 * (i >> 2) + 4 * h;  // 0..15
                const float2 mi = MI[p * 16 + lr];
                #pragma unroll
                for (int t = 0; t < 8; ++t)
                    lbuf[lr * 516 + wn * 256 + t * 32 + c5] =
                        __expf(20.f * acc[t][rr] - csqv[t] - mi.x) * mi.y;
            }
        }
        __syncthreads();
        #pragma unroll
        for (int j = 0; j < 8; ++j) {
            const int f    = j * 256 + tid;     // 0..2047 float4 slots
            const int lrow = f >> 7;            // 0..15
            const int c4   = f & 127;
            float4    v    = *(const float4*)&lbuf[lrow * 516 + c4 * 4];
            *(float4*)(out + (size_t)(row0 + p * 16 + lrow) * KC + c4 * 4) = v;
        }
        __syncthreads();
    }
}

extern "C" void kernel_launch(void* const* d_in, const int* in_sizes, int n_in,
                              void* d_out, int out_size, void* d_ws, size_t ws_size,
                              hipStream_t stream) {
    const float* x   = (const float*)d_in[0];
    const float* c   = (const float*)d_in[1];
    float*       out = (float*)d_out;

    unsigned short* bhi   = (unsigned short*)d_ws;                 // 256 KB
    unsigned short* blo   = bhi + (size_t)KCH * CHUNK_USH;         // 256 KB
    float*          csq10 = (float*)(blo + (size_t)KCH * CHUNK_USH);  // 2 KB

    prep_c<<<KC, 64, 0, stream>>>(c, bhi, blo, csq10);
    kmeans_mfma<<<NROWS / BM, 256, 0, stream>>>(x, bhi, blo, csq10, out);
}